// Round 1
// baseline (2683.574 us; speedup 1.0000x reference)
//
#include <hip/hip_runtime.h>
#include <math.h>

#define NROW 1024
#define DIN  128
#define DOUT 256
#define MEMN 65536

// ---------------- static device scratch (ws_size unknown -> self-owned) ----
__device__ float g_fn[NROW * DOUT];                 // 1 MB
__device__ float g_bank2[(size_t)MEMN * DOUT];      // 64 MB
__device__ float g_pairs[(size_t)NROW * MEMN];      // 256 MB
__device__ int   g_owner[MEMN];
__device__ unsigned short g_meta[MEMN];             // label+1 if flag2>0 else 0
__device__ float g_flag2[MEMN];
__device__ float g_possum[NROW];
__device__ float g_negsum[NROW];
__device__ float g_pos[NROW * 8];
__device__ float g_neg[NROW * 32];
__device__ int   g_rndc[NROW * 32];
__device__ float g_rowloss[NROW];
__device__ int   g_rowvalid[NROW];

// ---------------- threefry2x32 exactly as JAX lowers it (key = (0,1)) ------
__device__ __forceinline__ void tfround(unsigned &x0, unsigned &x1, int r) {
  x0 += x1; x1 = (x1 << r) | (x1 >> (32 - r)); x1 ^= x0;
}
__device__ __forceinline__ unsigned threefry_out(unsigned x0, unsigned x1, bool hi) {
  const unsigned ks1 = 1u, ks2 = 0x1BD11BDBu;       // ks0 = 0, parity = 0x1BD11BDA
  x1 += ks1;                                        // x0 += ks0 (=0)
  tfround(x0,x1,13); tfround(x0,x1,15); tfround(x0,x1,26); tfround(x0,x1,6);
  x0 += ks1; x1 += ks2 + 1u;
  tfround(x0,x1,17); tfround(x0,x1,29); tfround(x0,x1,16); tfround(x0,x1,24);
  x0 += ks2; x1 += 2u;
  tfround(x0,x1,13); tfround(x0,x1,15); tfround(x0,x1,26); tfround(x0,x1,6);
  x1 += ks1 + 3u;
  tfround(x0,x1,17); tfround(x0,x1,29); tfround(x0,x1,16); tfround(x0,x1,24);
  x0 += ks1; x1 += ks2 + 4u;
  tfround(x0,x1,13); tfround(x0,x1,15); tfround(x0,x1,26); tfround(x0,x1,6);
  x0 += ks2; x1 += 5u;
  return hi ? x1 : x0;
}

// ---------------- prep kernels ---------------------------------------------
__global__ void k_owner_init() {
  int j = blockIdx.x * 256 + threadIdx.x;
  if (j < MEMN) g_owner[j] = -1;
}
__global__ void k_owner_scatter(const long long* idx) {
  int i = blockIdx.x * 256 + threadIdx.x;
  if (i < NROW) atomicMax(&g_owner[(int)idx[i]], i);   // last occurrence wins
}
__global__ void k_meta(const float* bank_flag, const int* label_all) {
  int j = blockIdx.x * 256 + threadIdx.x;
  if (j >= MEMN) return;
  float fl = (g_owner[j] >= 0) ? 1.0f : bank_flag[j];
  g_flag2[j] = fl;
  g_meta[j] = (fl > 0.0f) ? (unsigned short)(label_all[j] + 1) : (unsigned short)0;
}

// fn = normalize(f @ W^T + b), one block per row
__global__ __launch_bounds__(256) void k_fn(const float* f, const float* W, const float* b) {
  int i = blockIdx.x, t = threadIdx.x;
  __shared__ __align__(16) float sf[DIN];
  __shared__ float sred[256];
  if (t < DIN / 4) ((float4*)sf)[t] = ((const float4*)(f + (size_t)i * DIN))[t];
  __syncthreads();
  const float4* wrow = (const float4*)(W + (size_t)t * DIN);
  float acc = 0.0f;
  #pragma unroll
  for (int k = 0; k < DIN / 4; ++k) {
    float4 wv = wrow[k]; float4 fv = ((float4*)sf)[k];
    acc = fmaf(wv.x, fv.x, acc); acc = fmaf(wv.y, fv.y, acc);
    acc = fmaf(wv.z, fv.z, acc); acc = fmaf(wv.w, fv.w, acc);
  }
  acc += b[t];
  sred[t] = acc * acc;
  __syncthreads();
  for (int s = 128; s > 0; s >>= 1) { if (t < s) sred[t] += sred[t + s]; __syncthreads(); }
  float rinv = 1.0f / sqrtf(sred[0]);
  g_fn[(size_t)i * DOUT + t] = acc * rinv;
}

// Bank2 = Bank with owner rows replaced by fn rows
__global__ __launch_bounds__(64) void k_bank2(const float* Bank) {
  int j = blockIdx.x, t = threadIdx.x;
  int own = g_owner[j];
  const float4* src = (own >= 0) ? (const float4*)(g_fn + (size_t)own * DOUT)
                                 : (const float4*)(Bank + (size_t)j * DOUT);
  ((float4*)(g_bank2 + (size_t)j * DOUT))[t] = src[t];
}

// ---------------- pairs = fn @ bank2^T : 1024 x 65536 x 256 fp32 -----------
#define BM 64
#define BN 64
#define BK 32
__global__ __launch_bounds__(256) void k_gemm() {
  __shared__ __align__(16) float As[BK][BM + 4];
  __shared__ __align__(16) float Bs[BK][BN + 4];
  const int tid = threadIdx.x;
  const int row0 = blockIdx.y * BM, col0 = blockIdx.x * BN;
  const int r0 = (tid >> 4) << 2, c0 = (tid & 15) << 2;
  float acc[4][4] = {};
  for (int kt = 0; kt < DOUT; kt += BK) {
    #pragma unroll
    for (int it = 0; it < 2; ++it) {
      int q = it * 256 + tid;
      int rr = q >> 3, kq = (q & 7) << 2;
      float4 v = *(const float4*)(g_fn + (size_t)(row0 + rr) * DOUT + kt + kq);
      As[kq + 0][rr] = v.x; As[kq + 1][rr] = v.y; As[kq + 2][rr] = v.z; As[kq + 3][rr] = v.w;
      float4 w = *(const float4*)(g_bank2 + (size_t)(col0 + rr) * DOUT + kt + kq);
      Bs[kq + 0][rr] = w.x; Bs[kq + 1][rr] = w.y; Bs[kq + 2][rr] = w.z; Bs[kq + 3][rr] = w.w;
    }
    __syncthreads();
    #pragma unroll
    for (int k = 0; k < BK; ++k) {
      float4 a4 = *(const float4*)&As[k][r0];
      float4 b4 = *(const float4*)&Bs[k][c0];
      float av[4] = {a4.x, a4.y, a4.z, a4.w};
      float bw[4] = {b4.x, b4.y, b4.z, b4.w};
      #pragma unroll
      for (int rr = 0; rr < 4; ++rr)
        #pragma unroll
        for (int cc = 0; cc < 4; ++cc)
          acc[rr][cc] = fmaf(av[rr], bw[cc], acc[rr][cc]);
    }
    __syncthreads();
  }
  #pragma unroll
  for (int rr = 0; rr < 4; ++rr) {
    float4 o = make_float4(acc[rr][0], acc[rr][1], acc[rr][2], acc[rr][3]);
    *(float4*)(g_pairs + (size_t)(row0 + r0 + rr) * MEMN + col0 + c0) = o;
  }
}

// ---------------- per-row selection (1 block = 1 row, 4 waves) -------------
__global__ __launch_bounds__(256) void k_select(const int* label) {
  const int row = blockIdx.x;
  const int tid = threadIdx.x;
  const int lane = tid & 63;
  const int wid = tid >> 6;
  const int lab = label[row] + 1;
  const bool hi = (row >= 512);
  // flat uniform index F = row*65536 + j; H = 2^25.
  // lo rows: (x0,x1) = (F, F+H), take out0.  hi rows: (F-H, F), take out1.
  const unsigned Fb = hi ? ((unsigned)(row - 512) << 16) : ((unsigned)row << 16);

  float ng[32], rp[32], pv[8];
  int rc[32];
  #pragma unroll
  for (int s = 0; s < 32; ++s) { ng[s] = -3.0e38f; rp[s] = -1.0f; rc[s] = 0x7fffffff; }
  #pragma unroll
  for (int s = 0; s < 8; ++s) pv[s] = 3.0e38f;
  float psum = 0.0f, nsum = 0.0f;
  const float* prow = g_pairs + (size_t)row * MEMN;

  #pragma unroll 1
  for (int t = 0; t < 64; ++t) {
    const int j0 = (t * 256 + tid) * 4;
    float4 pr4 = *(const float4*)(prow + j0);
    float4 fl4 = *(const float4*)(g_flag2 + j0);
    unsigned long long mw = *(const unsigned long long*)(g_meta + j0);
    float prv[4] = {pr4.x, pr4.y, pr4.z, pr4.w};
    float flv[4] = {fl4.x, fl4.y, fl4.z, fl4.w};
    #pragma unroll
    for (int q = 0; q < 4; ++q) {
      const int m = (int)((mw >> (16 * q)) & 0xffffULL);
      if (m == 0) continue;
      const float v = prv[q];
      if (m == lab) {                       // positive
        psum += flv[q];
        if (v < pv[7]) {                    // keep 8 smallest
          #pragma unroll
          for (int s = 7; s >= 1; --s) pv[s] = (v < pv[s]) ? ((v < pv[s-1]) ? pv[s-1] : v) : pv[s];
          pv[0] = (v < pv[0]) ? v : pv[0];
        }
      } else {                              // negative
        nsum += flv[q];
        if (v > ng[31]) {                   // keep 32 largest
          #pragma unroll
          for (int s = 31; s >= 1; --s) ng[s] = (v > ng[s]) ? ((v > ng[s-1]) ? ng[s-1] : v) : ng[s];
          ng[0] = (v > ng[0]) ? v : ng[0];
        }
        const int j = j0 + q;
        const unsigned x0 = Fb + (unsigned)j;
        const unsigned bits = threefry_out(x0, x0 + 0x2000000u, hi);
        const float pri = __uint_as_float((bits >> 9) | 0x3f800000u) - 1.0f;
        if (pri > rp[31] || (pri == rp[31] && j < rc[31])) {  // keep 32 largest priorities
          #pragma unroll
          for (int s = 31; s >= 1; --s) {
            bool g1 = (pri > rp[s])   || (pri == rp[s]   && j < rc[s]);
            bool g0 = (pri > rp[s-1]) || (pri == rp[s-1] && j < rc[s-1]);
            float np = g1 ? (g0 ? rp[s-1] : pri) : rp[s];
            int   nc = g1 ? (g0 ? rc[s-1] : j)   : rc[s];
            rp[s] = np; rc[s] = nc;
          }
          if (pri > rp[0] || (pri == rp[0] && j < rc[0])) { rp[0] = pri; rc[0] = j; }
        }
      }
    }
  }

  // wave-reduce sums
  #pragma unroll
  for (int off = 32; off; off >>= 1) {
    psum += __shfl_xor(psum, off);
    nsum += __shfl_xor(nsum, off);
  }
  __shared__ float s_ps[4], s_ns[4];
  __shared__ float s_negw[128];
  __shared__ float s_rpw[128];
  __shared__ int   s_rcw[128];
  __shared__ float s_posw[32];
  if (lane == 0) { s_ps[wid] = psum; s_ns[wid] = nsum; }

  // wave top-32 negatives (pop-extraction, head = reg[0])
  #pragma unroll 1
  for (int r = 0; r < 32; ++r) {
    float bv = ng[0]; int bl = lane;
    #pragma unroll
    for (int off = 32; off; off >>= 1) {
      float ov = __shfl_xor(bv, off); int ol = __shfl_xor(bl, off);
      if (ov > bv || (ov == bv && ol < bl)) { bv = ov; bl = ol; }
    }
    if (lane == 0) s_negw[wid * 32 + r] = bv;
    if (lane == bl) {
      #pragma unroll
      for (int s = 0; s < 31; ++s) ng[s] = ng[s + 1];
      ng[31] = -3.0e38f;
    }
  }
  // wave top-32 random priorities (tie -> lower column)
  #pragma unroll 1
  for (int r = 0; r < 32; ++r) {
    float bp = rp[0]; int bc = rc[0]; int bl = lane;
    #pragma unroll
    for (int off = 32; off; off >>= 1) {
      float op = __shfl_xor(bp, off); int oc = __shfl_xor(bc, off); int ol = __shfl_xor(bl, off);
      bool take = (op > bp) || (op == bp && (oc < bc || (oc == bc && ol < bl)));
      if (take) { bp = op; bc = oc; bl = ol; }
    }
    if (lane == 0) { s_rpw[wid * 32 + r] = bp; s_rcw[wid * 32 + r] = bc; }
    if (lane == bl) {
      #pragma unroll
      for (int s = 0; s < 31; ++s) { rp[s] = rp[s + 1]; rc[s] = rc[s + 1]; }
      rp[31] = -1.0f; rc[31] = 0x7fffffff;
    }
  }
  // wave top-8 positives (smallest)
  #pragma unroll 1
  for (int r = 0; r < 8; ++r) {
    float bv = pv[0]; int bl = lane;
    #pragma unroll
    for (int off = 32; off; off >>= 1) {
      float ov = __shfl_xor(bv, off); int ol = __shfl_xor(bl, off);
      if (ov < bv || (ov == bv && ol < bl)) { bv = ov; bl = ol; }
    }
    if (lane == 0) s_posw[wid * 8 + r] = bv;
    if (lane == bl) {
      #pragma unroll
      for (int s = 0; s < 7; ++s) pv[s] = pv[s + 1];
      pv[7] = 3.0e38f;
    }
  }
  __syncthreads();

  // cross-wave merges, one structure per wave
  if (wid == 0) {           // negatives: 128 candidates -> top 32
    float a = s_negw[lane], c = s_negw[64 + lane];
    float hh = fmaxf(a, c), ll = fminf(a, c);
    #pragma unroll 1
    for (int r = 0; r < 32; ++r) {
      float bv = hh; int bl = lane;
      #pragma unroll
      for (int off = 32; off; off >>= 1) {
        float ov = __shfl_xor(bv, off); int ol = __shfl_xor(bl, off);
        if (ov > bv || (ov == bv && ol < bl)) { bv = ov; bl = ol; }
      }
      if (lane == 0) g_neg[row * 32 + r] = bv;
      if (lane == bl) { hh = ll; ll = -3.0e38f; }
    }
    if (lane == 0) {
      g_possum[row] = s_ps[0] + s_ps[1] + s_ps[2] + s_ps[3];
      g_negsum[row] = s_ns[0] + s_ns[1] + s_ns[2] + s_ns[3];
    }
  } else if (wid == 1) {    // random: 128 (pri,col) -> top 32 cols
    float p1 = s_rpw[lane];      int c1 = s_rcw[lane];
    float p2 = s_rpw[64 + lane]; int c2 = s_rcw[64 + lane];
    bool sw = (p2 > p1) || (p2 == p1 && c2 < c1);
    float ph = sw ? p2 : p1; int ch = sw ? c2 : c1;
    float pl = sw ? p1 : p2; int cl = sw ? c1 : c2;
    #pragma unroll 1
    for (int r = 0; r < 32; ++r) {
      float bp = ph; int bc = ch; int bl = lane;
      #pragma unroll
      for (int off = 32; off; off >>= 1) {
        float op = __shfl_xor(bp, off); int oc = __shfl_xor(bc, off); int ol = __shfl_xor(bl, off);
        bool take = (op > bp) || (op == bp && (oc < bc || (oc == bc && ol < bl)));
        if (take) { bp = op; bc = oc; bl = ol; }
      }
      if (lane == 0) g_rndc[row * 32 + r] = bc;
      if (lane == bl) { ph = pl; ch = cl; pl = -1.0f; cl = 0x7fffffff; }
    }
  } else if (wid == 2) {    // positives: 32 candidates -> 8 smallest
    float a = (lane < 32) ? s_posw[lane] : 3.0e38f;
    #pragma unroll 1
    for (int r = 0; r < 8; ++r) {
      float bv = a; int bl = lane;
      #pragma unroll
      for (int off = 32; off; off >>= 1) {
        float ov = __shfl_xor(bv, off); int ol = __shfl_xor(bl, off);
        if (ov < bv || (ov == bv && ol < bl)) { bv = ov; bl = ol; }
      }
      if (lane == 0) g_pos[row * 8 + r] = bv;
      if (lane == bl) a = 3.0e38f;
    }
  }
}

// ---------------- per-row loss ---------------------------------------------
__global__ __launch_bounds__(256) void k_loss() {
  int i = blockIdx.x * 256 + threadIdx.x;
  if (i >= NROW) return;
  float psum = g_possum[i], nsum = g_negsum[i];
  int valid = (psum >= 8.0f) && (nsum >= 32.0f);
  float loss = 0.0f;
  if (valid) {
    const float invT = 1.25f;   // 1/0.8 exact
    float nh[32], nr[32];
    float m1 = -3.0e38f, m2 = -3.0e38f;
    #pragma unroll
    for (int k = 0; k < 32; ++k) {
      nh[k] = g_neg[i * 32 + k] * invT; m1 = fmaxf(m1, nh[k]);
      int c = g_rndc[i * 32 + k];
      nr[k] = g_pairs[(size_t)i * MEMN + c] * invT; m2 = fmaxf(m2, nr[k]);
    }
    float s1 = 0.0f, s2 = 0.0f;
    #pragma unroll
    for (int k = 0; k < 32; ++k) { s1 += expf(nh[k] - m1); s2 += expf(nr[k] - m2); }
    #pragma unroll
    for (int p = 0; p < 8; ++p) {
      float a = g_pos[i * 8 + p] * invT;
      { float m = fmaxf(a, m1); loss += m + logf(expf(a - m) + s1 * expf(m1 - m)) - a; }
      { float m = fmaxf(a, m2); loss += m + logf(expf(a - m) + s2 * expf(m2 - m)) - a; }
    }
  }
  g_rowloss[i] = loss;
  g_rowvalid[i] = valid;
}

__global__ __launch_bounds__(256) void k_final(float* out) {
  __shared__ float sl[256];
  __shared__ int sc[256];
  int t = threadIdx.x;
  float l = 0.0f; int c = 0;
  for (int i = t; i < NROW; i += 256) { l += g_rowloss[i]; c += g_rowvalid[i]; }
  sl[t] = l; sc[t] = c;
  __syncthreads();
  for (int s = 128; s > 0; s >>= 1) {
    if (t < s) { sl[t] += sl[t + s]; sc[t] += sc[t + s]; }
    __syncthreads();
  }
  if (t == 0) out[0] = (sc[0] > 0) ? sl[0] / ((float)sc[0] * 16.0f) : 0.0f;
}

// ---------------- launch ----------------------------------------------------
extern "C" void kernel_launch(void* const* d_in, const int* in_sizes, int n_in,
                              void* d_out, int out_size, void* d_ws, size_t ws_size,
                              hipStream_t stream) {
  const float* f          = (const float*)d_in[0];
  const float* W          = (const float*)d_in[1];
  const float* b          = (const float*)d_in[2];
  const float* Bank       = (const float*)d_in[3];
  const float* bank_flag  = (const float*)d_in[4];
  const int*   label      = (const int*)d_in[5];
  const long long* in_idx = (const long long*)d_in[6];
  const int*   label_all  = (const int*)d_in[7];
  float* out = (float*)d_out;

  hipLaunchKernelGGL(k_owner_init,    dim3(MEMN / 256), dim3(256), 0, stream);
  hipLaunchKernelGGL(k_owner_scatter, dim3(NROW / 256), dim3(256), 0, stream, in_idx);
  hipLaunchKernelGGL(k_meta,          dim3(MEMN / 256), dim3(256), 0, stream, bank_flag, label_all);
  hipLaunchKernelGGL(k_fn,            dim3(NROW),       dim3(256), 0, stream, f, W, b);
  hipLaunchKernelGGL(k_bank2,         dim3(MEMN),       dim3(64),  0, stream, Bank);
  hipLaunchKernelGGL(k_gemm,          dim3(MEMN / BN, NROW / BM), dim3(256), 0, stream);
  hipLaunchKernelGGL(k_select,        dim3(NROW),       dim3(256), 0, stream, label);
  hipLaunchKernelGGL(k_loss,          dim3(NROW / 256), dim3(256), 0, stream);
  hipLaunchKernelGGL(k_final,         dim3(1),          dim3(256), 0, stream, out);
}

// Round 2
// 386.996 us; speedup vs baseline: 6.9344x; 6.9344x over previous
//
#include <hip/hip_runtime.h>
#include <math.h>

#define NROW 1024
#define DIN  128
#define DOUT 256
#define MEMN 65536

typedef __attribute__((ext_vector_type(8))) short bf16x8;
typedef __attribute__((ext_vector_type(4))) float f32x4;
typedef __attribute__((ext_vector_type(8))) unsigned short u16x8;

// ---------------- static device scratch ------------------------------------
__device__ float          g_fn[NROW * DOUT];                 // 1 MB f32
__device__ unsigned short g_fnb[NROW * DOUT];                // bf16
__device__ unsigned short g_bank2b[(size_t)MEMN * DOUT];     // 32 MB bf16
__device__ unsigned short g_pairsb[(size_t)NROW * MEMN];     // 128 MB bf16
__device__ int            g_owner[MEMN];
__device__ unsigned short g_meta[MEMN];                      // label+1 if flag2>0 else 0
__device__ float          g_flag2[MEMN];
__device__ float          g_possum[NROW];
__device__ float          g_negsum[NROW];
__device__ float          g_pos[NROW * 8];
__device__ float          g_neg[NROW * 32];
__device__ float          g_rnd[NROW * 32];
__device__ float          g_rowloss[NROW];
__device__ int            g_rowvalid[NROW];

__device__ __forceinline__ unsigned short f2bf(float x) {
  union { float f; unsigned u; } c; c.f = x;
  unsigned r = c.u + 0x7fffu + ((c.u >> 16) & 1u);   // RNE
  return (unsigned short)(r >> 16);
}
__device__ __forceinline__ float bf2f(unsigned short b) {
  return __uint_as_float((unsigned)b << 16);
}

// ---------------- threefry2x32, key=(0,1) — bit-exact validated R0 ---------
__device__ __forceinline__ void tfround(unsigned &x0, unsigned &x1, int r) {
  x0 += x1; x1 = (x1 << r) | (x1 >> (32 - r)); x1 ^= x0;
}
__device__ __forceinline__ unsigned threefry_out(unsigned x0, unsigned x1, bool hi) {
  const unsigned ks1 = 1u, ks2 = 0x1BD11BDBu;
  x1 += ks1;
  tfround(x0,x1,13); tfround(x0,x1,15); tfround(x0,x1,26); tfround(x0,x1,6);
  x0 += ks1; x1 += ks2 + 1u;
  tfround(x0,x1,17); tfround(x0,x1,29); tfround(x0,x1,16); tfround(x0,x1,24);
  x0 += ks2; x1 += 2u;
  tfround(x0,x1,13); tfround(x0,x1,15); tfround(x0,x1,26); tfround(x0,x1,6);
  x1 += ks1 + 3u;
  tfround(x0,x1,17); tfround(x0,x1,29); tfround(x0,x1,16); tfround(x0,x1,24);
  x0 += ks1; x1 += ks2 + 4u;
  tfround(x0,x1,13); tfround(x0,x1,15); tfround(x0,x1,26); tfround(x0,x1,6);
  x0 += ks2; x1 += 5u;
  return hi ? x1 : x0;
}

// ---------------- prep kernels ----------------------------------------------
__global__ void k_owner_init() {
  int j = blockIdx.x * 256 + threadIdx.x;
  if (j < MEMN) g_owner[j] = -1;
}
__global__ void k_owner_scatter(const long long* idx) {
  int i = blockIdx.x * 256 + threadIdx.x;
  if (i < NROW) atomicMax(&g_owner[(int)idx[i]], i);   // last occurrence wins
}
__global__ void k_meta(const float* bank_flag, const int* label_all) {
  int j = blockIdx.x * 256 + threadIdx.x;
  if (j >= MEMN) return;
  float fl = (g_owner[j] >= 0) ? 1.0f : bank_flag[j];
  g_flag2[j] = fl;
  g_meta[j] = (fl > 0.0f) ? (unsigned short)(label_all[j] + 1) : (unsigned short)0;
}

// fn = normalize(f @ W^T + b), one block per row; writes f32 + bf16
__global__ __launch_bounds__(256) void k_fn(const float* f, const float* W, const float* b) {
  int i = blockIdx.x, t = threadIdx.x;
  __shared__ __align__(16) float sf[DIN];
  __shared__ float sred[256];
  if (t < DIN / 4) ((float4*)sf)[t] = ((const float4*)(f + (size_t)i * DIN))[t];
  __syncthreads();
  const float4* wrow = (const float4*)(W + (size_t)t * DIN);
  float acc = 0.0f;
  #pragma unroll
  for (int k = 0; k < DIN / 4; ++k) {
    float4 wv = wrow[k]; float4 fv = ((float4*)sf)[k];
    acc = fmaf(wv.x, fv.x, acc); acc = fmaf(wv.y, fv.y, acc);
    acc = fmaf(wv.z, fv.z, acc); acc = fmaf(wv.w, fv.w, acc);
  }
  acc += b[t];
  sred[t] = acc * acc;
  __syncthreads();
  for (int s = 128; s > 0; s >>= 1) { if (t < s) sred[t] += sred[t + s]; __syncthreads(); }
  float v = acc * (1.0f / sqrtf(sred[0]));
  g_fn[(size_t)i * DOUT + t] = v;
  g_fnb[(size_t)i * DOUT + t] = f2bf(v);
}

// bank2 (bf16) = Bank with owner rows replaced by fn rows
__global__ __launch_bounds__(64) void k_bank2(const float* Bank) {
  int j = blockIdx.x, t = threadIdx.x;
  int own = g_owner[j];
  const float4* src = (own >= 0) ? (const float4*)(g_fn + (size_t)own * DOUT)
                                 : (const float4*)(Bank + (size_t)j * DOUT);
  float4 v = src[t];
  unsigned lo = (unsigned)f2bf(v.x) | ((unsigned)f2bf(v.y) << 16);
  unsigned hi = (unsigned)f2bf(v.z) | ((unsigned)f2bf(v.w) << 16);
  ((uint2*)(g_bank2b + (size_t)j * DOUT))[t] = make_uint2(lo, hi);
}

// ---------------- pairs = fn @ bank2^T via bf16 MFMA ------------------------
// 128x128 tile, BK=32, 4 waves (2x2), 16x16x32 MFMA, global_load_lds staging.
#define GBK 32
__device__ __forceinline__ void gload16(const void* g, void* l) {
  __builtin_amdgcn_global_load_lds((const __attribute__((address_space(1))) void*)g,
                                   (__attribute__((address_space(3))) void*)l, 16, 0, 0);
}

__global__ __launch_bounds__(256) void k_gemm() {
  __shared__ __align__(16) unsigned short lds[2][2][128 * GBK];  // [dbuf][A|B]
  const int tid = threadIdx.x, lane = tid & 63, w = tid >> 6;
  // XCD swizzle: XCD x owns col-tiles [64x,64x+64), rows consecutive per col
  int bid = blockIdx.x;                       // 0..4095
  int swz = (bid & 7) * 512 + (bid >> 3);
  const int row0 = (swz & 7) * 128, col0 = (swz >> 3) * 128;
  const int wm = w >> 1, wn = w & 1;

  f32x4 acc[4][4];
  #pragma unroll
  for (int i = 0; i < 4; ++i)
    #pragma unroll
    for (int j = 0; j < 4; ++j) acc[i][j] = (f32x4){0.f, 0.f, 0.f, 0.f};

  // fragment LDS offsets (ushort units); XOR-swizzled chunk index
  int aoff[4], boff[4];
  #pragma unroll
  for (int mf = 0; mf < 4; ++mf) {
    int ra = wm * 64 + mf * 16 + (lane & 15);
    int ca = (lane >> 4) ^ ((ra >> 1) & 3);
    aoff[mf] = ra * GBK + ca * 8;
    int rb = wn * 64 + mf * 16 + (lane & 15);
    int cb = (lane >> 4) ^ ((rb >> 1) & 3);
    boff[mf] = rb * GBK + cb * 8;
  }

  auto stage = [&](int buf, int kt) {
    #pragma unroll
    for (int q = 0; q < 2; ++q) {
      int g  = w * 2 + q;          // 0..7 per tile
      int ci = g * 64 + lane;      // chunk 0..511
      int r  = ci >> 2, c = ci & 3;
      int cs = c ^ ((r >> 1) & 3); // pre-swizzled global source (rule #21)
      gload16(g_fnb    + (size_t)(row0 + r) * DOUT + kt + cs * 8, &lds[buf][0][g * 512]);
      gload16(g_bank2b + (size_t)(col0 + r) * DOUT + kt + cs * 8, &lds[buf][1][g * 512]);
    }
  };

  stage(0, 0);
  __syncthreads();
  int cur = 0;
  for (int kt = 0; kt < DOUT; kt += GBK) {
    if (kt + GBK < DOUT) stage(cur ^ 1, kt + GBK);
    bf16x8 af[4], bf_[4];
    #pragma unroll
    for (int mf = 0; mf < 4; ++mf) af[mf]  = *(const bf16x8*)&lds[cur][0][aoff[mf]];
    #pragma unroll
    for (int nf = 0; nf < 4; ++nf) bf_[nf] = *(const bf16x8*)&lds[cur][1][boff[nf]];
    #pragma unroll
    for (int mf = 0; mf < 4; ++mf)
      #pragma unroll
      for (int nf = 0; nf < 4; ++nf)
        acc[mf][nf] = __builtin_amdgcn_mfma_f32_16x16x32_bf16(af[mf], bf_[nf], acc[mf][nf], 0, 0, 0);
    __syncthreads();
    cur ^= 1;
  }

  // epilogue: C/D layout col=lane&15, row=(lane>>4)*4+reg  [m89/m91]
  #pragma unroll
  for (int mf = 0; mf < 4; ++mf) {
    int rb = row0 + wm * 64 + mf * 16 + ((lane >> 4) << 2);
    #pragma unroll
    for (int nf = 0; nf < 4; ++nf) {
      int cg = col0 + wn * 64 + nf * 16 + (lane & 15);
      #pragma unroll
      for (int jj = 0; jj < 4; ++jj)
        g_pairsb[(size_t)(rb + jj) * MEMN + cg] = f2bf(acc[mf][nf][jj]);
    }
  }
}

// ---------------- per-row selection: histogram + filter ---------------------
__global__ __launch_bounds__(256) void k_select(const int* label) {
  const int row = blockIdx.x, tid = threadIdx.x, lane = tid & 63, wid = tid >> 6;
  __shared__ unsigned int s_hist[4][1024];
  __shared__ float s_pos[1024];
  __shared__ float s_priv[512];
  __shared__ int   s_pric[512];
  __shared__ float s_ncv[512];
  __shared__ int s_pcnt, s_prcnt, s_ncnt;
  __shared__ float s_ps[4], s_ns[4];
  __shared__ float s_vth;

  for (int i = tid; i < 4096; i += 256) ((unsigned int*)s_hist)[i] = 0u;
  if (tid == 0) { s_pcnt = 0; s_prcnt = 0; s_ncnt = 0; }
  __syncthreads();

  const int lab = label[row] + 1;
  const bool hif = row >= 512;
  const unsigned Fb = (unsigned)(hif ? (row - 512) : row) << 16;
  const unsigned short* prow = g_pairsb + (size_t)row * MEMN;
  float psum = 0.f, nsum = 0.f;

  // pass 1: hist + sums + pos list + priority candidates
  #pragma unroll 1
  for (int it = 0; it < 32; ++it) {
    int j0 = (it * 256 + tid) * 8;
    u16x8 pb = *(const u16x8*)(prow + j0);
    u16x8 mb = *(const u16x8*)(g_meta + j0);
    float fl[8];
    *(float4*)&fl[0] = *(const float4*)(g_flag2 + j0);
    *(float4*)&fl[4] = *(const float4*)(g_flag2 + j0 + 4);
    #pragma unroll
    for (int q = 0; q < 8; ++q) {
      int m = mb[q];
      if (m == 0) continue;
      float v = bf2f(pb[q]);
      if (m == lab) {
        psum += fl[q];
        int p = atomicAdd(&s_pcnt, 1);
        if (p < 1024) s_pos[p] = v;
      } else {
        nsum += fl[q];
        int bin = (int)((v + 1.0f) * 512.0f);
        bin = bin < 0 ? 0 : (bin > 1023 ? 1023 : bin);
        atomicAdd(&s_hist[wid][bin], 1u);
        unsigned x0 = Fb + (unsigned)(j0 + q);
        unsigned bits = threefry_out(x0, x0 + 0x2000000u, hif);
        float pri = __uint_as_float((bits >> 9) | 0x3f800000u) - 1.0f;
        if (pri >= 0.998f) {
          int p = atomicAdd(&s_prcnt, 1);
          if (p < 512) { s_priv[p] = pri; s_pric[p] = j0 + q; }
        }
      }
    }
  }
  #pragma unroll
  for (int off = 32; off; off >>= 1) { psum += __shfl_xor(psum, off); nsum += __shfl_xor(nsum, off); }
  if (lane == 0) { s_ps[wid] = psum; s_ns[wid] = nsum; }
  __syncthreads();

  if (tid == 0) {
    g_possum[row] = s_ps[0] + s_ps[1] + s_ps[2] + s_ps[3];
    g_negsum[row] = s_ns[0] + s_ns[1] + s_ns[2] + s_ns[3];
    int cum = 0, B = 0;
    for (int b = 1023; b >= 0; --b) {
      cum += s_hist[0][b] + s_hist[1][b] + s_hist[2][b] + s_hist[3][b];
      if (cum >= 32) { B = b; break; }
    }
    s_vth = (float)B * (1.0f / 512.0f) - 1.0f;   // exact dyadic edge
  }
  __syncthreads();
  const float vth = s_vth;

  // pass 2: collect negative candidates >= bin edge
  #pragma unroll 1
  for (int it = 0; it < 32; ++it) {
    int j0 = (it * 256 + tid) * 8;
    u16x8 pb = *(const u16x8*)(prow + j0);
    u16x8 mb = *(const u16x8*)(g_meta + j0);
    #pragma unroll
    for (int q = 0; q < 8; ++q) {
      int m = mb[q];
      if (m == 0 || m == lab) continue;
      float v = bf2f(pb[q]);
      if (v >= vth) { int p = atomicAdd(&s_ncnt, 1); if (p < 512) s_ncv[p] = v; }
    }
  }
  __syncthreads();

  int nc  = s_ncnt  < 512  ? s_ncnt  : 512;
  int prc = s_prcnt < 512  ? s_prcnt : 512;
  int pc  = s_pcnt  < 1024 ? s_pcnt  : 1024;

  if (wid == 0) {                       // exact top-32 negatives
    float vals[8];
    #pragma unroll
    for (int q = 0; q < 8; ++q) { int ix = q * 64 + lane; vals[q] = ix < nc ? s_ncv[ix] : -3.0e38f; }
    float myv = -3.0e38f;
    #pragma unroll 1
    for (int r = 0; r < 32; ++r) {
      float bv = vals[0]; int bq = 0;
      #pragma unroll
      for (int q = 1; q < 8; ++q) { bool t = vals[q] > bv; bv = t ? vals[q] : bv; bq = t ? q : bq; }
      int bl = lane;
      #pragma unroll
      for (int off = 32; off; off >>= 1) {
        float ov = __shfl_xor(bv, off); int ol = __shfl_xor(bl, off);
        bool t = ov > bv || (ov == bv && ol < bl);
        bv = t ? ov : bv; bl = t ? ol : bl;
      }
      if (lane == bl) {
        #pragma unroll
        for (int q = 0; q < 8; ++q) vals[q] = (q == bq) ? -3.0e38f : vals[q];
      }
      if (lane == r) myv = bv;
    }
    if (lane < 32) g_neg[row * 32 + lane] = myv;
  } else if (wid == 1) {                // exact top-32 priorities (tie: lower col)
    float pvv[8]; int pcc[8];
    #pragma unroll
    for (int q = 0; q < 8; ++q) {
      int ix = q * 64 + lane; bool ok = ix < prc;
      pvv[q] = ok ? s_priv[ix] : -1.0f; pcc[q] = ok ? s_pric[ix] : 0x7fffffff;
    }
    int mycol = -1;
    #pragma unroll 1
    for (int r = 0; r < 32; ++r) {
      float bp = pvv[0]; int bc = pcc[0]; int bq = 0;
      #pragma unroll
      for (int q = 1; q < 8; ++q) {
        bool t = pvv[q] > bp || (pvv[q] == bp && pcc[q] < bc);
        bp = t ? pvv[q] : bp; bc = t ? pcc[q] : bc; bq = t ? q : bq;
      }
      int bl = lane;
      #pragma unroll
      for (int off = 32; off; off >>= 1) {
        float op = __shfl_xor(bp, off); int oc = __shfl_xor(bc, off); int ol = __shfl_xor(bl, off);
        bool t = op > bp || (op == bp && (oc < bc || (oc == bc && ol < bl)));
        bp = t ? op : bp; bc = t ? oc : bc; bl = t ? ol : bl;
      }
      if (lane == bl) {
        #pragma unroll
        for (int q = 0; q < 8; ++q) { pvv[q] = (q == bq) ? -1.0f : pvv[q]; pcc[q] = (q == bq) ? 0x7fffffff : pcc[q]; }
      }
      if (lane == r) mycol = bc;
    }
    if (lane < 32) {
      float v = (mycol >= 0 && mycol < MEMN) ? bf2f(prow[mycol]) : 0.0f;
      g_rnd[row * 32 + lane] = v;
    }
  } else if (wid == 2) {                // exact 8 smallest positives
    float vals[16];
    #pragma unroll
    for (int q = 0; q < 16; ++q) { int ix = q * 64 + lane; vals[q] = ix < pc ? s_pos[ix] : 3.0e38f; }
    float myv = 3.0e38f;
    #pragma unroll 1
    for (int r = 0; r < 8; ++r) {
      float bv = vals[0]; int bq = 0;
      #pragma unroll
      for (int q = 1; q < 16; ++q) { bool t = vals[q] < bv; bv = t ? vals[q] : bv; bq = t ? q : bq; }
      int bl = lane;
      #pragma unroll
      for (int off = 32; off; off >>= 1) {
        float ov = __shfl_xor(bv, off); int ol = __shfl_xor(bl, off);
        bool t = ov < bv || (ov == bv && ol < bl);
        bv = t ? ov : bv; bl = t ? ol : bl;
      }
      if (lane == bl) {
        #pragma unroll
        for (int q = 0; q < 16; ++q) vals[q] = (q == bq) ? 3.0e38f : vals[q];
      }
      if (lane == r) myv = bv;
    }
    if (lane < 8) g_pos[row * 8 + lane] = myv;
  }
}

// ---------------- per-row loss ----------------------------------------------
__global__ __launch_bounds__(256) void k_loss() {
  int i = blockIdx.x * 256 + threadIdx.x;
  if (i >= NROW) return;
  float psum = g_possum[i], nsum = g_negsum[i];
  int valid = (psum >= 8.0f) && (nsum >= 32.0f);
  float loss = 0.0f;
  if (valid) {
    const float invT = 1.25f;
    float nh[32], nr[32];
    float m1 = -3.0e38f, m2 = -3.0e38f;
    #pragma unroll
    for (int k = 0; k < 32; ++k) {
      nh[k] = g_neg[i * 32 + k] * invT; m1 = fmaxf(m1, nh[k]);
      nr[k] = g_rnd[i * 32 + k] * invT; m2 = fmaxf(m2, nr[k]);
    }
    float s1 = 0.0f, s2 = 0.0f;
    #pragma unroll
    for (int k = 0; k < 32; ++k) { s1 += expf(nh[k] - m1); s2 += expf(nr[k] - m2); }
    #pragma unroll
    for (int p = 0; p < 8; ++p) {
      float a = g_pos[i * 8 + p] * invT;
      { float m = fmaxf(a, m1); loss += m + logf(expf(a - m) + s1 * expf(m1 - m)) - a; }
      { float m = fmaxf(a, m2); loss += m + logf(expf(a - m) + s2 * expf(m2 - m)) - a; }
    }
  }
  g_rowloss[i] = loss;
  g_rowvalid[i] = valid;
}

__global__ __launch_bounds__(256) void k_final(float* out) {
  __shared__ float sl[256];
  __shared__ int sc[256];
  int t = threadIdx.x;
  float l = 0.0f; int c = 0;
  for (int i = t; i < NROW; i += 256) { l += g_rowloss[i]; c += g_rowvalid[i]; }
  sl[t] = l; sc[t] = c;
  __syncthreads();
  for (int s = 128; s > 0; s >>= 1) {
    if (t < s) { sl[t] += sl[t + s]; sc[t] += sc[t + s]; }
    __syncthreads();
  }
  if (t == 0) out[0] = (sc[0] > 0) ? sl[0] / ((float)sc[0] * 16.0f) : 0.0f;
}

// ---------------- launch ----------------------------------------------------
extern "C" void kernel_launch(void* const* d_in, const int* in_sizes, int n_in,
                              void* d_out, int out_size, void* d_ws, size_t ws_size,
                              hipStream_t stream) {
  const float* f          = (const float*)d_in[0];
  const float* W          = (const float*)d_in[1];
  const float* b          = (const float*)d_in[2];
  const float* Bank       = (const float*)d_in[3];
  const float* bank_flag  = (const float*)d_in[4];
  const int*   label      = (const int*)d_in[5];
  const long long* in_idx = (const long long*)d_in[6];
  const int*   label_all  = (const int*)d_in[7];
  float* out = (float*)d_out;

  hipLaunchKernelGGL(k_owner_init,    dim3(MEMN / 256), dim3(256), 0, stream);
  hipLaunchKernelGGL(k_owner_scatter, dim3(NROW / 256), dim3(256), 0, stream, in_idx);
  hipLaunchKernelGGL(k_meta,          dim3(MEMN / 256), dim3(256), 0, stream, bank_flag, label_all);
  hipLaunchKernelGGL(k_fn,            dim3(NROW),       dim3(256), 0, stream, f, W, b);
  hipLaunchKernelGGL(k_bank2,         dim3(MEMN),       dim3(64),  0, stream, Bank);
  hipLaunchKernelGGL(k_gemm,          dim3(4096),       dim3(256), 0, stream);
  hipLaunchKernelGGL(k_select,        dim3(NROW),       dim3(256), 0, stream, label);
  hipLaunchKernelGGL(k_loss,          dim3(NROW / 256), dim3(256), 0, stream);
  hipLaunchKernelGGL(k_final,         dim3(1),          dim3(256), 0, stream, out);
}

// Round 3
// 352.680 us; speedup vs baseline: 7.6091x; 1.0973x over previous
//
#include <hip/hip_runtime.h>
#include <math.h>

#define NROW 1024
#define DIN  128
#define DOUT 256
#define MEMN 65536
#define QTH  8371831u   // bits>>9 threshold == pri >= ~0.998 (way below 32nd-largest of 65k)

typedef __attribute__((ext_vector_type(8))) short bf16x8;
typedef __attribute__((ext_vector_type(4))) float f32x4;
typedef __attribute__((ext_vector_type(8))) unsigned short u16x8;

// ---------------- static device scratch ------------------------------------
__device__ float          g_fn[NROW * DOUT];
__device__ unsigned short g_fnb[NROW * DOUT];
__device__ unsigned short g_bank2b[(size_t)MEMN * DOUT];
__device__ unsigned short g_pairsb[(size_t)NROW * MEMN];     // 128 MB bf16
__device__ int            g_owner[MEMN];
__device__ unsigned short g_meta[MEMN];                      // label+1 if flag2>0 else 0
__device__ float          g_clssum[156];                     // [c]=flag-weighted count, [155]=total
__device__ float          g_pos[NROW * 8];
__device__ float          g_neg[NROW * 32];
__device__ int            g_rndc[NROW * 32];
__device__ float          g_rowloss[NROW];
__device__ int            g_rowvalid[NROW];

__device__ __forceinline__ unsigned short f2bf(float x) {
  union { float f; unsigned u; } c; c.f = x;
  unsigned r = c.u + 0x7fffu + ((c.u >> 16) & 1u);   // RNE
  return (unsigned short)(r >> 16);
}
__device__ __forceinline__ float bf2f(unsigned short b) {
  return __uint_as_float((unsigned)b << 16);
}

// ---------------- threefry2x32, key=(0,1) — bit-exact (validated R0/R1) ----
__device__ __forceinline__ void tfround(unsigned &x0, unsigned &x1, int r) {
  x0 += x1; x1 = (x1 << r) | (x1 >> (32 - r)); x1 ^= x0;
}
// one hash serves elements F (out x0) and F+2^25 (out x1)
__device__ __forceinline__ uint2 threefry_both(unsigned x0, unsigned x1) {
  const unsigned ks1 = 1u, ks2 = 0x1BD11BDBu;
  x1 += ks1;
  tfround(x0,x1,13); tfround(x0,x1,15); tfround(x0,x1,26); tfround(x0,x1,6);
  x0 += ks1; x1 += ks2 + 1u;
  tfround(x0,x1,17); tfround(x0,x1,29); tfround(x0,x1,16); tfround(x0,x1,24);
  x0 += ks2; x1 += 2u;
  tfround(x0,x1,13); tfround(x0,x1,15); tfround(x0,x1,26); tfround(x0,x1,6);
  x1 += ks1 + 3u;
  tfround(x0,x1,17); tfround(x0,x1,29); tfround(x0,x1,16); tfround(x0,x1,24);
  x0 += ks1; x1 += ks2 + 4u;
  tfround(x0,x1,13); tfround(x0,x1,15); tfround(x0,x1,26); tfround(x0,x1,6);
  x0 += ks2; x1 += 5u;
  return make_uint2(x0, x1);
}

// ---------------- prep kernels ----------------------------------------------
__global__ void k_owner_init() {
  int j = blockIdx.x * 256 + threadIdx.x;
  g_owner[j] = -1;
  if (j < 156) g_clssum[j] = 0.0f;
}
__global__ void k_owner_scatter(const long long* idx) {
  int i = blockIdx.x * 256 + threadIdx.x;
  if (i < NROW) atomicMax(&g_owner[(int)idx[i]], i);   // last occurrence wins
}
// meta + per-class flag-weighted counts (exact: flags are 0/1)
__global__ void k_meta(const float* bank_flag, const int* label_all) {
  __shared__ float s_cls[156];
  int t = threadIdx.x;
  int j = blockIdx.x * 256 + t;
  if (t < 156) s_cls[t] = 0.0f;
  __syncthreads();
  float fl = (g_owner[j] >= 0) ? 1.0f : bank_flag[j];
  int la = label_all[j];
  unsigned short m = (fl > 0.0f) ? (unsigned short)(la + 1) : (unsigned short)0;
  g_meta[j] = m;
  if (m) { atomicAdd(&s_cls[la], fl); atomicAdd(&s_cls[155], fl); }
  __syncthreads();
  if (t < 156 && s_cls[t] != 0.0f) atomicAdd(&g_clssum[t], s_cls[t]);
}

// fn = normalize(f @ W^T + b)
__global__ __launch_bounds__(256) void k_fn(const float* f, const float* W, const float* b) {
  int i = blockIdx.x, t = threadIdx.x;
  __shared__ __align__(16) float sf[DIN];
  __shared__ float sred[256];
  if (t < DIN / 4) ((float4*)sf)[t] = ((const float4*)(f + (size_t)i * DIN))[t];
  __syncthreads();
  const float4* wrow = (const float4*)(W + (size_t)t * DIN);
  float acc = 0.0f;
  #pragma unroll
  for (int k = 0; k < DIN / 4; ++k) {
    float4 wv = wrow[k]; float4 fv = ((float4*)sf)[k];
    acc = fmaf(wv.x, fv.x, acc); acc = fmaf(wv.y, fv.y, acc);
    acc = fmaf(wv.z, fv.z, acc); acc = fmaf(wv.w, fv.w, acc);
  }
  acc += b[t];
  sred[t] = acc * acc;
  __syncthreads();
  for (int s = 128; s > 0; s >>= 1) { if (t < s) sred[t] += sred[t + s]; __syncthreads(); }
  float v = acc * (1.0f / sqrtf(sred[0]));
  g_fn[(size_t)i * DOUT + t] = v;
  g_fnb[(size_t)i * DOUT + t] = f2bf(v);
}

__global__ __launch_bounds__(64) void k_bank2(const float* Bank) {
  int j = blockIdx.x, t = threadIdx.x;
  int own = g_owner[j];
  const float4* src = (own >= 0) ? (const float4*)(g_fn + (size_t)own * DOUT)
                                 : (const float4*)(Bank + (size_t)j * DOUT);
  float4 v = src[t];
  unsigned lo = (unsigned)f2bf(v.x) | ((unsigned)f2bf(v.y) << 16);
  unsigned hi = (unsigned)f2bf(v.z) | ((unsigned)f2bf(v.w) << 16);
  ((uint2*)(g_bank2b + (size_t)j * DOUT))[t] = make_uint2(lo, hi);
}

// ---------------- random-negative columns: pure threefry, no pairs dep ------
// Block b handles rows b and b+512 (they share hashes: elements F and F+2^25).
__global__ __launch_bounds__(512) void k_rand(const int* label) {
  const int rlo = blockIdx.x;
  const int tid = threadIdx.x, lane = tid & 63, wid = tid >> 6;
  __shared__ unsigned s_cv[2][512];
  __shared__ int s_cj[2][512];
  __shared__ int s_cnt[2];
  if (tid < 2) s_cnt[tid] = 0;
  __syncthreads();
  const int lab0 = label[rlo] + 1, lab1 = label[rlo + 512] + 1;
  const unsigned base = (unsigned)rlo << 16;
  #pragma unroll 2
  for (int it = 0; it < 128; ++it) {
    unsigned j = (unsigned)(it * 512 + tid);
    unsigned x0 = base + j;
    uint2 o = threefry_both(x0, x0 + 0x2000000u);
    unsigned q0 = o.x >> 9, q1 = o.y >> 9;
    if (q0 >= QTH || q1 >= QTH) {
      int m = g_meta[j];
      if (m) {
        if (q0 >= QTH && m != lab0) { int p = atomicAdd(&s_cnt[0], 1); if (p < 512) { s_cv[0][p] = q0; s_cj[0][p] = (int)j; } }
        if (q1 >= QTH && m != lab1) { int p = atomicAdd(&s_cnt[1], 1); if (p < 512) { s_cv[1][p] = q1; s_cj[1][p] = (int)j; } }
      }
    }
  }
  __syncthreads();
  if (wid < 2) {
    int cnt = s_cnt[wid] < 512 ? s_cnt[wid] : 512;
    unsigned kv[8]; int kj[8];
    #pragma unroll
    for (int q = 0; q < 8; ++q) {
      int ix = q * 64 + lane; bool ok = ix < cnt;
      kv[q] = ok ? s_cv[wid][ix] : 0u;
      kj[q] = ok ? s_cj[wid][ix] : 0x7fffffff;
    }
    int myc = 0;
    #pragma unroll 1
    for (int r = 0; r < 32; ++r) {
      unsigned bq = kv[0]; int bc = kj[0]; int bqi = 0;
      #pragma unroll
      for (int q = 1; q < 8; ++q) {
        bool t = kv[q] > bq || (kv[q] == bq && kj[q] < bc);
        bq = t ? kv[q] : bq; bc = t ? kj[q] : bc; bqi = t ? q : bqi;
      }
      int bl = lane;
      #pragma unroll
      for (int off = 32; off; off >>= 1) {
        unsigned oq = __shfl_xor(bq, off); int oc = __shfl_xor(bc, off); int ol = __shfl_xor(bl, off);
        bool t = oq > bq || (oq == bq && (oc < bc || (oc == bc && ol < bl)));
        bq = t ? oq : bq; bc = t ? oc : bc; bl = t ? ol : bl;
      }
      if (lane == bl) {
        #pragma unroll
        for (int q = 0; q < 8; ++q) { kv[q] = (q == bqi) ? 0u : kv[q]; kj[q] = (q == bqi) ? 0x7fffffff : kj[q]; }
      }
      if (lane == r) myc = bc;
    }
    if (lane < 32) g_rndc[(rlo + wid * 512) * 32 + lane] = myc;
  }
}

// ---------------- pairs = fn @ bank2^T via bf16 MFMA ------------------------
#define GBK 32
__device__ __forceinline__ void gload16(const void* g, void* l) {
  __builtin_amdgcn_global_load_lds((const __attribute__((address_space(1))) void*)g,
                                   (__attribute__((address_space(3))) void*)l, 16, 0, 0);
}

__global__ __launch_bounds__(256) void k_gemm() {
  __shared__ __align__(16) unsigned short lds[2][2][128 * GBK];
  const int tid = threadIdx.x, lane = tid & 63, w = tid >> 6;
  int bid = blockIdx.x;
  int swz = (bid & 7) * 512 + (bid >> 3);
  const int row0 = (swz & 7) * 128, col0 = (swz >> 3) * 128;
  const int wm = w >> 1, wn = w & 1;

  f32x4 acc[4][4];
  #pragma unroll
  for (int i = 0; i < 4; ++i)
    #pragma unroll
    for (int j = 0; j < 4; ++j) acc[i][j] = (f32x4){0.f, 0.f, 0.f, 0.f};

  int aoff[4], boff[4];
  #pragma unroll
  for (int mf = 0; mf < 4; ++mf) {
    int ra = wm * 64 + mf * 16 + (lane & 15);
    int ca = (lane >> 4) ^ ((ra >> 1) & 3);
    aoff[mf] = ra * GBK + ca * 8;
    int rb = wn * 64 + mf * 16 + (lane & 15);
    int cb = (lane >> 4) ^ ((rb >> 1) & 3);
    boff[mf] = rb * GBK + cb * 8;
  }

  auto stage = [&](int buf, int kt) {
    #pragma unroll
    for (int q = 0; q < 2; ++q) {
      int g  = w * 2 + q;
      int ci = g * 64 + lane;
      int r  = ci >> 2, c = ci & 3;
      int cs = c ^ ((r >> 1) & 3);
      gload16(g_fnb    + (size_t)(row0 + r) * DOUT + kt + cs * 8, &lds[buf][0][g * 512]);
      gload16(g_bank2b + (size_t)(col0 + r) * DOUT + kt + cs * 8, &lds[buf][1][g * 512]);
    }
  };

  stage(0, 0);
  __syncthreads();
  int cur = 0;
  for (int kt = 0; kt < DOUT; kt += GBK) {
    if (kt + GBK < DOUT) stage(cur ^ 1, kt + GBK);
    bf16x8 af[4], bf_[4];
    #pragma unroll
    for (int mf = 0; mf < 4; ++mf) af[mf]  = *(const bf16x8*)&lds[cur][0][aoff[mf]];
    #pragma unroll
    for (int nf = 0; nf < 4; ++nf) bf_[nf] = *(const bf16x8*)&lds[cur][1][boff[nf]];
    #pragma unroll
    for (int mf = 0; mf < 4; ++mf)
      #pragma unroll
      for (int nf = 0; nf < 4; ++nf)
        acc[mf][nf] = __builtin_amdgcn_mfma_f32_16x16x32_bf16(af[mf], bf_[nf], acc[mf][nf], 0, 0, 0);
    __syncthreads();
    cur ^= 1;
  }

  #pragma unroll
  for (int mf = 0; mf < 4; ++mf) {
    int rb = row0 + wm * 64 + mf * 16 + ((lane >> 4) << 2);
    #pragma unroll
    for (int nf = 0; nf < 4; ++nf) {
      int cg = col0 + wn * 64 + nf * 16 + (lane & 15);
      #pragma unroll
      for (int jj = 0; jj < 4; ++jj)
        g_pairsb[(size_t)(rb + jj) * MEMN + cg] = f2bf(acc[mf][nf][jj]);
    }
  }
}

// ---------------- per-row hard selection (hist + filter, no threefry) -------
__global__ __launch_bounds__(256) void k_select(const int* label) {
  const int row = blockIdx.x, tid = threadIdx.x, lane = tid & 63, wid = tid >> 6;
  __shared__ unsigned s_hist[4][1024];
  __shared__ float s_pos[1024];
  __shared__ float s_ncv[512];
  __shared__ int s_pcnt, s_ncnt;
  __shared__ float s_vth;

  for (int i = tid; i < 4096; i += 256) ((unsigned*)s_hist)[i] = 0u;
  if (tid == 0) { s_pcnt = 0; s_ncnt = 0; }
  __syncthreads();

  const int lab = label[row] + 1;
  const unsigned short* prow = g_pairsb + (size_t)row * MEMN;

  // pass 1: hist (negatives) + positive values
  #pragma unroll 1
  for (int it = 0; it < 32; ++it) {
    int j0 = (it * 256 + tid) * 8;
    u16x8 pb = *(const u16x8*)(prow + j0);
    u16x8 mb = *(const u16x8*)(g_meta + j0);
    #pragma unroll
    for (int q = 0; q < 8; ++q) {
      int m = mb[q];
      if (m == 0) continue;
      float v = bf2f(pb[q]);
      if (m == lab) {
        int p = atomicAdd(&s_pcnt, 1); if (p < 1024) s_pos[p] = v;
      } else {
        int bin = (int)((v + 1.0f) * 512.0f);
        bin = bin < 0 ? 0 : (bin > 1023 ? 1023 : bin);
        atomicAdd(&s_hist[wid][bin], 1u);
      }
    }
  }
  __syncthreads();

  // parallel pivot: total per bin -> chunk suffix -> ballot -> in-chunk scan
  for (int b = tid; b < 1024; b += 256) {
    unsigned t4 = s_hist[0][b] + s_hist[1][b] + s_hist[2][b] + s_hist[3][b];
    s_hist[0][b] = t4;
  }
  __syncthreads();
  if (wid == 0) {
    unsigned cs = 0;
    #pragma unroll
    for (int i = 0; i < 16; ++i) cs += s_hist[0][lane * 16 + i];
    unsigned sfx = cs;
    #pragma unroll
    for (int off = 1; off < 64; off <<= 1) {
      unsigned t = __shfl_down(sfx, off);
      if (lane + off < 64) sfx += t;
    }
    unsigned long long mask = __ballot(sfx >= 32u);
    int C = (mask == 0ull) ? -1 : (63 - __clzll(mask));
    unsigned above = (C >= 0 && C < 63) ? __shfl(sfx, (C + 1) & 63) : 0u;
    if (lane == 0) {
      if (C < 0) s_vth = 3.0e38f;          // <32 negatives: row invalid anyway
      else {
        unsigned cum = above; int B = C * 16;
        for (int i = 15; i >= 0; --i) {
          cum += s_hist[0][C * 16 + i];
          if (cum >= 32u) { B = C * 16 + i; break; }
        }
        s_vth = (float)B * (1.0f / 512.0f) - 1.0f;   // exact dyadic edge
      }
    }
  }
  __syncthreads();
  const float vth = s_vth;

  // pass 2: collect negatives >= pivot edge (L2-resident re-read)
  #pragma unroll 1
  for (int it = 0; it < 32; ++it) {
    int j0 = (it * 256 + tid) * 8;
    u16x8 pb = *(const u16x8*)(prow + j0);
    u16x8 mb = *(const u16x8*)(g_meta + j0);
    #pragma unroll
    for (int q = 0; q < 8; ++q) {
      int m = mb[q];
      if (m == 0 || m == lab) continue;
      float v = bf2f(pb[q]);
      if (v >= vth) { int p = atomicAdd(&s_ncnt, 1); if (p < 512) s_ncv[p] = v; }
    }
  }
  __syncthreads();

  int nc = s_ncnt < 512 ? s_ncnt : 512;
  int pc = s_pcnt < 1024 ? s_pcnt : 1024;

  if (wid == 0) {                       // exact top-32 negatives
    float vals[8];
    #pragma unroll
    for (int q = 0; q < 8; ++q) { int ix = q * 64 + lane; vals[q] = ix < nc ? s_ncv[ix] : -3.0e38f; }
    float myv = -3.0e38f;
    #pragma unroll 1
    for (int r = 0; r < 32; ++r) {
      float bv = vals[0]; int bq = 0;
      #pragma unroll
      for (int q = 1; q < 8; ++q) { bool t = vals[q] > bv; bv = t ? vals[q] : bv; bq = t ? q : bq; }
      int bl = lane;
      #pragma unroll
      for (int off = 32; off; off >>= 1) {
        float ov = __shfl_xor(bv, off); int ol = __shfl_xor(bl, off);
        bool t = ov > bv || (ov == bv && ol < bl);
        bv = t ? ov : bv; bl = t ? ol : bl;
      }
      if (lane == bl) {
        #pragma unroll
        for (int q = 0; q < 8; ++q) vals[q] = (q == bq) ? -3.0e38f : vals[q];
      }
      if (lane == r) myv = bv;
    }
    if (lane < 32) g_neg[row * 32 + lane] = myv;
  } else if (wid == 2) {                // exact 8 smallest positives
    float vals[16];
    #pragma unroll
    for (int q = 0; q < 16; ++q) { int ix = q * 64 + lane; vals[q] = ix < pc ? s_pos[ix] : 3.0e38f; }
    float myv = 3.0e38f;
    #pragma unroll 1
    for (int r = 0; r < 8; ++r) {
      float bv = vals[0]; int bq = 0;
      #pragma unroll
      for (int q = 1; q < 16; ++q) { bool t = vals[q] < bv; bv = t ? vals[q] : bv; bq = t ? q : bq; }
      int bl = lane;
      #pragma unroll
      for (int off = 32; off; off >>= 1) {
        float ov = __shfl_xor(bv, off); int ol = __shfl_xor(bl, off);
        bool t = ov < bv || (ov == bv && ol < bl);
        bv = t ? ov : bv; bl = t ? ol : bl;
      }
      if (lane == bl) {
        #pragma unroll
        for (int q = 0; q < 16; ++q) vals[q] = (q == bq) ? 3.0e38f : vals[q];
      }
      if (lane == r) myv = bv;
    }
    if (lane < 8) g_pos[row * 8 + lane] = myv;
  }
}

// ---------------- per-row loss ----------------------------------------------
__global__ __launch_bounds__(256) void k_loss(const int* label) {
  int i = blockIdx.x * 256 + threadIdx.x;
  if (i >= NROW) return;
  float psum = g_clssum[label[i]];
  float nsum = g_clssum[155] - psum;
  int valid = (psum >= 8.0f) && (nsum >= 32.0f);
  float loss = 0.0f;
  if (valid) {
    const float invT = 1.25f;
    float nh[32], nr[32];
    float m1 = -3.0e38f, m2 = -3.0e38f;
    #pragma unroll
    for (int k = 0; k < 32; ++k) {
      nh[k] = g_neg[i * 32 + k] * invT; m1 = fmaxf(m1, nh[k]);
      int c = g_rndc[i * 32 + k]; c = ((unsigned)c < MEMN) ? c : 0;
      nr[k] = bf2f(g_pairsb[(size_t)i * MEMN + c]) * invT; m2 = fmaxf(m2, nr[k]);
    }
    float s1 = 0.0f, s2 = 0.0f;
    #pragma unroll
    for (int k = 0; k < 32; ++k) { s1 += expf(nh[k] - m1); s2 += expf(nr[k] - m2); }
    #pragma unroll
    for (int p = 0; p < 8; ++p) {
      float a = g_pos[i * 8 + p] * invT;
      { float m = fmaxf(a, m1); loss += m + logf(expf(a - m) + s1 * expf(m1 - m)) - a; }
      { float m = fmaxf(a, m2); loss += m + logf(expf(a - m) + s2 * expf(m2 - m)) - a; }
    }
  }
  g_rowloss[i] = loss;
  g_rowvalid[i] = valid;
}

__global__ __launch_bounds__(256) void k_final(float* out) {
  __shared__ float sl[256];
  __shared__ int sc[256];
  int t = threadIdx.x;
  float l = 0.0f; int c = 0;
  for (int i = t; i < NROW; i += 256) { l += g_rowloss[i]; c += g_rowvalid[i]; }
  sl[t] = l; sc[t] = c;
  __syncthreads();
  for (int s = 128; s > 0; s >>= 1) {
    if (t < s) { sl[t] += sl[t + s]; sc[t] += sc[t + s]; }
    __syncthreads();
  }
  if (t == 0) out[0] = (sc[0] > 0) ? sl[0] / ((float)sc[0] * 16.0f) : 0.0f;
}

// ---------------- launch ----------------------------------------------------
extern "C" void kernel_launch(void* const* d_in, const int* in_sizes, int n_in,
                              void* d_out, int out_size, void* d_ws, size_t ws_size,
                              hipStream_t stream) {
  const float* f          = (const float*)d_in[0];
  const float* W          = (const float*)d_in[1];
  const float* b          = (const float*)d_in[2];
  const float* Bank       = (const float*)d_in[3];
  const float* bank_flag  = (const float*)d_in[4];
  const int*   label      = (const int*)d_in[5];
  const long long* in_idx = (const long long*)d_in[6];
  const int*   label_all  = (const int*)d_in[7];
  float* out = (float*)d_out;

  hipLaunchKernelGGL(k_owner_init,    dim3(MEMN / 256), dim3(256), 0, stream);
  hipLaunchKernelGGL(k_owner_scatter, dim3(NROW / 256), dim3(256), 0, stream, in_idx);
  hipLaunchKernelGGL(k_meta,          dim3(MEMN / 256), dim3(256), 0, stream, bank_flag, label_all);
  hipLaunchKernelGGL(k_fn,            dim3(NROW),       dim3(256), 0, stream, f, W, b);
  hipLaunchKernelGGL(k_bank2,         dim3(MEMN),       dim3(64),  0, stream, Bank);
  hipLaunchKernelGGL(k_rand,          dim3(NROW / 2),   dim3(512), 0, stream, label);
  hipLaunchKernelGGL(k_gemm,          dim3(4096),       dim3(256), 0, stream);
  hipLaunchKernelGGL(k_select,        dim3(NROW),       dim3(256), 0, stream, label);
  hipLaunchKernelGGL(k_loss,          dim3(NROW / 256), dim3(256), 0, stream, label);
  hipLaunchKernelGGL(k_final,         dim3(1),          dim3(256), 0, stream, out);
}

// Round 4
// 342.754 us; speedup vs baseline: 7.8294x; 1.0290x over previous
//
#include <hip/hip_runtime.h>
#include <math.h>

#define NROW 1024
#define DIN  128
#define DOUT 256
#define MEMN 65536
#define QTH  8371831u   // bits>>9 threshold; mean ~131 candidates/row pass

typedef __attribute__((ext_vector_type(8))) short bf16x8;
typedef __attribute__((ext_vector_type(4))) float f32x4;
typedef __attribute__((ext_vector_type(8))) unsigned short u16x8;

// ---------------- static device scratch ------------------------------------
__device__ unsigned short g_fnb[NROW * DOUT];
__device__ unsigned short g_bank2b[(size_t)MEMN * DOUT];
__device__ unsigned short g_pairsb[(size_t)NROW * MEMN];     // 128 MB bf16
__device__ int            g_owner[MEMN];
__device__ unsigned short g_meta[MEMN];                      // label+1 if flag2>0 else 0
__device__ float          g_clssum[156];                     // [c]=flag count, [155]=total
__device__ float          g_pos[NROW * 8];
__device__ float          g_neg[NROW * 32];
__device__ int            g_rndc[NROW * 32];
__device__ float          g_rowloss[NROW];
__device__ int            g_rowvalid[NROW];

__device__ __forceinline__ unsigned short f2bf(float x) {
  union { float f; unsigned u; } c; c.f = x;
  unsigned r = c.u + 0x7fffu + ((c.u >> 16) & 1u);   // RNE
  return (unsigned short)(r >> 16);
}
__device__ __forceinline__ float bf2f(unsigned short b) {
  return __uint_as_float((unsigned)b << 16);
}

// ---------------- threefry2x32 key=(0,1), ILP-2 interleaved ----------------
#define ROTL(x, r) (((x) << (r)) | ((x) >> (32 - (r))))
#define TF_R2(r) { a0 += a1; a1 = ROTL(a1, r); a1 ^= a0; \
                   b0 += b1; b1 = ROTL(b1, r); b1 ^= b0; }
__device__ __forceinline__ void tf2(unsigned &a0, unsigned &a1, unsigned &b0, unsigned &b1) {
  const unsigned ks1 = 1u, ks2 = 0x1BD11BDBu;
  a1 += ks1; b1 += ks1;
  TF_R2(13) TF_R2(15) TF_R2(26) TF_R2(6)
  a0 += ks1; a1 += ks2 + 1u; b0 += ks1; b1 += ks2 + 1u;
  TF_R2(17) TF_R2(29) TF_R2(16) TF_R2(24)
  a0 += ks2; a1 += 2u;       b0 += ks2; b1 += 2u;
  TF_R2(13) TF_R2(15) TF_R2(26) TF_R2(6)
  a1 += ks1 + 3u;            b1 += ks1 + 3u;
  TF_R2(17) TF_R2(29) TF_R2(16) TF_R2(24)
  a0 += ks1; a1 += ks2 + 4u; b0 += ks1; b1 += ks2 + 4u;
  TF_R2(13) TF_R2(15) TF_R2(26) TF_R2(6)
  a0 += ks2; a1 += 5u;       b0 += ks2; b1 += 5u;
}

// ---------------- prep kernels ----------------------------------------------
__global__ void k_owner_init() {
  int j = blockIdx.x * 256 + threadIdx.x;
  g_owner[j] = -1;
  if (j < 156) g_clssum[j] = 0.0f;
}
__global__ void k_owner_scatter(const long long* idx) {
  int i = blockIdx.x * 256 + threadIdx.x;
  if (i < NROW) atomicMax(&g_owner[(int)idx[i]], i);   // last occurrence wins
}
__global__ void k_meta(const float* bank_flag, const int* label_all) {
  __shared__ float s_cls[156];
  int t = threadIdx.x;
  int j = blockIdx.x * 256 + t;
  if (t < 156) s_cls[t] = 0.0f;
  __syncthreads();
  float fl = (g_owner[j] >= 0) ? 1.0f : bank_flag[j];
  int la = label_all[j];
  unsigned short m = (fl > 0.0f) ? (unsigned short)(la + 1) : (unsigned short)0;
  g_meta[j] = m;
  if (m) { atomicAdd(&s_cls[la], fl); atomicAdd(&s_cls[155], fl); }
  __syncthreads();
  if (t < 156 && s_cls[t] != 0.0f) atomicAdd(&g_clssum[t], s_cls[t]);
}

// fn = normalize(f @ W^T + b) -> bf16
__global__ __launch_bounds__(256) void k_fn(const float* f, const float* W, const float* b) {
  int i = blockIdx.x, t = threadIdx.x;
  __shared__ __align__(16) float sf[DIN];
  __shared__ float sred[256];
  if (t < DIN / 4) ((float4*)sf)[t] = ((const float4*)(f + (size_t)i * DIN))[t];
  __syncthreads();
  const float4* wrow = (const float4*)(W + (size_t)t * DIN);
  float acc = 0.0f;
  #pragma unroll
  for (int k = 0; k < DIN / 4; ++k) {
    float4 wv = wrow[k]; float4 fv = ((float4*)sf)[k];
    acc = fmaf(wv.x, fv.x, acc); acc = fmaf(wv.y, fv.y, acc);
    acc = fmaf(wv.z, fv.z, acc); acc = fmaf(wv.w, fv.w, acc);
  }
  acc += b[t];
  sred[t] = acc * acc;
  __syncthreads();
  for (int s = 128; s > 0; s >>= 1) { if (t < s) sred[t] += sred[t + s]; __syncthreads(); }
  g_fnb[(size_t)i * DOUT + t] = f2bf(acc * (1.0f / sqrtf(sred[0])));
}

// bank2 bf16: 4 rows per 256-thread block
__global__ __launch_bounds__(256) void k_bank2(const float* Bank) {
  int j = blockIdx.x * 4 + (threadIdx.x >> 6);
  int t = threadIdx.x & 63;
  int own = g_owner[j];
  uint2 o;
  if (own >= 0) {
    o = ((const uint2*)(g_fnb + (size_t)own * DOUT))[t];
  } else {
    float4 v = ((const float4*)(Bank + (size_t)j * DOUT))[t];
    o.x = (unsigned)f2bf(v.x) | ((unsigned)f2bf(v.y) << 16);
    o.y = (unsigned)f2bf(v.z) | ((unsigned)f2bf(v.w) << 16);
  }
  ((uint2*)(g_bank2b + (size_t)j * DOUT))[t] = o;
}

// ---------------- random-negative columns (threefry only) -------------------
// Block b: rows b and b+512 share hashes (elements F / F+2^25 -> out0/out1).
__global__ __launch_bounds__(512) void k_rand(const int* label) {
  const int rlo = blockIdx.x;
  const int tid = threadIdx.x, lane = tid & 63, wid = tid >> 6;
  __shared__ unsigned s_cv[2][512];
  __shared__ int s_cj[2][512];
  __shared__ int s_cnt[2];
  const int lab0 = label[rlo] + 1, lab1 = label[rlo + 512] + 1;
  const unsigned base = (unsigned)rlo << 16;

  unsigned th = QTH;
  for (;;) {                                     // fallback loop; 1 iter in practice
    if (tid < 2) s_cnt[tid] = 0;
    __syncthreads();
    #pragma unroll 1
    for (int it = 0; it < 64; ++it) {
      unsigned jA = (unsigned)(it * 512 + tid);
      unsigned jB = jA + 32768u;
      unsigned a0 = base + jA, a1 = a0 + 0x2000000u;
      unsigned b0 = base + jB, b1 = b0 + 0x2000000u;
      tf2(a0, a1, b0, b1);
      unsigned qA0 = a0 >> 9, qA1 = a1 >> 9, qB0 = b0 >> 9, qB1 = b1 >> 9;
      if (qA0 >= th || qA1 >= th || qB0 >= th || qB1 >= th) {
        int mA = g_meta[jA], mB = g_meta[jB];
        if (qA0 >= th && mA && mA != lab0) { int p = atomicAdd(&s_cnt[0], 1); if (p < 512) { s_cv[0][p] = qA0; s_cj[0][p] = (int)jA; } }
        if (qA1 >= th && mA && mA != lab1) { int p = atomicAdd(&s_cnt[1], 1); if (p < 512) { s_cv[1][p] = qA1; s_cj[1][p] = (int)jA; } }
        if (qB0 >= th && mB && mB != lab0) { int p = atomicAdd(&s_cnt[0], 1); if (p < 512) { s_cv[0][p] = qB0; s_cj[0][p] = (int)jB; } }
        if (qB1 >= th && mB && mB != lab1) { int p = atomicAdd(&s_cnt[1], 1); if (p < 512) { s_cv[1][p] = qB1; s_cj[1][p] = (int)jB; } }
      }
    }
    __syncthreads();
    if ((s_cnt[0] >= 32 && s_cnt[1] >= 32) || th == 0) break;
    th = (th * 2 > (1u << 23)) ? (th * 2 - (1u << 23)) : 0u;  // double the tail
  }

  if (wid < 2) {
    int cnt = s_cnt[wid] < 512 ? s_cnt[wid] : 512;
    unsigned kv[8]; int kj[8];
    #pragma unroll
    for (int q = 0; q < 8; ++q) {
      int ix = q * 64 + lane; bool ok = ix < cnt;
      kv[q] = ok ? s_cv[wid][ix] : 0u;
      kj[q] = ok ? s_cj[wid][ix] : 0x7fffffff;
    }
    int myc = 0;
    #pragma unroll 1
    for (int r = 0; r < 32; ++r) {
      unsigned bq = kv[0]; int bc = kj[0]; int bqi = 0;
      #pragma unroll
      for (int q = 1; q < 8; ++q) {
        bool t = kv[q] > bq || (kv[q] == bq && kj[q] < bc);
        bq = t ? kv[q] : bq; bc = t ? kj[q] : bc; bqi = t ? q : bqi;
      }
      int bl = lane;
      #pragma unroll
      for (int off = 32; off; off >>= 1) {
        unsigned oq = __shfl_xor(bq, off); int oc = __shfl_xor(bc, off); int ol = __shfl_xor(bl, off);
        bool t = oq > bq || (oq == bq && (oc < bc || (oc == bc && ol < bl)));
        bq = t ? oq : bq; bc = t ? oc : bc; bl = t ? ol : bl;
      }
      if (lane == bl) {
        #pragma unroll
        for (int q = 0; q < 8; ++q) { kv[q] = (q == bqi) ? 0u : kv[q]; kj[q] = (q == bqi) ? 0x7fffffff : kj[q]; }
      }
      if (lane == r) myc = bc;
    }
    if (lane < 32) g_rndc[(rlo + wid * 512) * 32 + lane] = myc;
  }
}

// ---------------- pairs = fn @ bank2^T via bf16 MFMA ------------------------
#define GBK 32
__device__ __forceinline__ void gload16(const void* g, void* l) {
  __builtin_amdgcn_global_load_lds((const __attribute__((address_space(1))) void*)g,
                                   (__attribute__((address_space(3))) void*)l, 16, 0, 0);
}

__global__ __launch_bounds__(256) void k_gemm() {
  __shared__ __align__(16) unsigned short lds[2][2][128 * GBK];
  const int tid = threadIdx.x, lane = tid & 63, w = tid >> 6;
  int bid = blockIdx.x;
  int swz = (bid & 7) * 512 + (bid >> 3);
  const int row0 = (swz & 7) * 128, col0 = (swz >> 3) * 128;
  const int wm = w >> 1, wn = w & 1;

  f32x4 acc[4][4];
  #pragma unroll
  for (int i = 0; i < 4; ++i)
    #pragma unroll
    for (int j = 0; j < 4; ++j) acc[i][j] = (f32x4){0.f, 0.f, 0.f, 0.f};

  int aoff[4], boff[4];
  #pragma unroll
  for (int mf = 0; mf < 4; ++mf) {
    int ra = wm * 64 + mf * 16 + (lane & 15);
    int ca = (lane >> 4) ^ ((ra >> 1) & 3);
    aoff[mf] = ra * GBK + ca * 8;
    int rb = wn * 64 + mf * 16 + (lane & 15);
    int cb = (lane >> 4) ^ ((rb >> 1) & 3);
    boff[mf] = rb * GBK + cb * 8;
  }

  auto stage = [&](int buf, int kt) {
    #pragma unroll
    for (int q = 0; q < 2; ++q) {
      int g  = w * 2 + q;
      int ci = g * 64 + lane;
      int r  = ci >> 2, c = ci & 3;
      int cs = c ^ ((r >> 1) & 3);
      gload16(g_fnb    + (size_t)(row0 + r) * DOUT + kt + cs * 8, &lds[buf][0][g * 512]);
      gload16(g_bank2b + (size_t)(col0 + r) * DOUT + kt + cs * 8, &lds[buf][1][g * 512]);
    }
  };

  stage(0, 0);
  __syncthreads();
  int cur = 0;
  for (int kt = 0; kt < DOUT; kt += GBK) {
    if (kt + GBK < DOUT) stage(cur ^ 1, kt + GBK);
    bf16x8 af[4], bf_[4];
    #pragma unroll
    for (int mf = 0; mf < 4; ++mf) af[mf]  = *(const bf16x8*)&lds[cur][0][aoff[mf]];
    #pragma unroll
    for (int nf = 0; nf < 4; ++nf) bf_[nf] = *(const bf16x8*)&lds[cur][1][boff[nf]];
    // swapped operands: D[c][r] layout -> per-lane 4 consecutive output COLUMNS
    #pragma unroll
    for (int mf = 0; mf < 4; ++mf)
      #pragma unroll
      for (int nf = 0; nf < 4; ++nf)
        acc[mf][nf] = __builtin_amdgcn_mfma_f32_16x16x32_bf16(bf_[nf], af[mf], acc[mf][nf], 0, 0, 0);
    __syncthreads();
    cur ^= 1;
  }

  // epilogue: row = fn row (lane&15), cols = 4 consecutive (packed 8B store)
  #pragma unroll
  for (int mf = 0; mf < 4; ++mf) {
    int rg = row0 + wm * 64 + mf * 16 + (lane & 15);
    #pragma unroll
    for (int nf = 0; nf < 4; ++nf) {
      int cg = col0 + wn * 64 + nf * 16 + ((lane >> 4) << 2);
      uint2 o;
      o.x = (unsigned)f2bf(acc[mf][nf][0]) | ((unsigned)f2bf(acc[mf][nf][1]) << 16);
      o.y = (unsigned)f2bf(acc[mf][nf][2]) | ((unsigned)f2bf(acc[mf][nf][3]) << 16);
      *(uint2*)(g_pairsb + (size_t)rg * MEMN + cg) = o;
    }
  }
}

// ---------------- per-row hard selection: fixed-floor filter ----------------
__global__ __launch_bounds__(256) void k_select(const int* label) {
  const int row = blockIdx.x, tid = threadIdx.x, lane = tid & 63, wid = tid >> 6;
  __shared__ float s_pos[1024];
  __shared__ float s_ncv[512];
  __shared__ int s_pcnt, s_ncnt;
  if (tid == 0) { s_pcnt = 0; s_ncnt = 0; }
  __syncthreads();

  const int lab = label[row] + 1;
  const unsigned short* prow = g_pairsb + (size_t)row * MEMN;
  const short FLOORB = 0x3E40;            // 0.1875 exact (bf16-bit signed compare)

  #pragma unroll 1
  for (int it = 0; it < 32; ++it) {
    int j0 = (it * 256 + tid) * 8;
    u16x8 pb = *(const u16x8*)(prow + j0);
    u16x8 mb = *(const u16x8*)(g_meta + j0);
    #pragma unroll
    for (int q = 0; q < 8; ++q) {
      int m = mb[q];
      if (m == lab) {
        int p = atomicAdd(&s_pcnt, 1); if (p < 1024) s_pos[p] = bf2f(pb[q]);
      } else if (m != 0 && (short)pb[q] >= FLOORB) {
        int p = atomicAdd(&s_ncnt, 1); if (p < 512) s_ncv[p] = bf2f(pb[q]);
      }
    }
  }
  __syncthreads();
  int nc = s_ncnt, pc = s_pcnt;

  // ---- negative fallback (exact; block-uniform; never taken on this data)
  if (nc < 32 || nc > 512) {
    float ng[32];
    #pragma unroll
    for (int s = 0; s < 32; ++s) ng[s] = -3.0e38f;
    #pragma unroll 1
    for (int it = 0; it < 32; ++it) {
      int j0 = (it * 256 + tid) * 8;
      u16x8 pb = *(const u16x8*)(prow + j0);
      u16x8 mb = *(const u16x8*)(g_meta + j0);
      #pragma unroll
      for (int q = 0; q < 8; ++q) {
        int m = mb[q];
        if (m == 0 || m == lab) continue;
        float v = bf2f(pb[q]);
        if (v > ng[31]) {
          #pragma unroll
          for (int s = 31; s >= 1; --s) ng[s] = (v > ng[s]) ? ((v > ng[s-1]) ? ng[s-1] : v) : ng[s];
          ng[0] = (v > ng[0]) ? v : ng[0];
        }
      }
    }
    __syncthreads();
    #pragma unroll 1
    for (int r = 0; r < 32; ++r) {       // per-wave pop top-32 -> 128 candidates
      float bv = ng[0]; int bl = lane;
      #pragma unroll
      for (int off = 32; off; off >>= 1) {
        float ov = __shfl_xor(bv, off); int ol = __shfl_xor(bl, off);
        bool t = ov > bv || (ov == bv && ol < bl);
        bv = t ? ov : bv; bl = t ? ol : bl;
      }
      if (lane == 0) s_ncv[wid * 32 + r] = bv;
      if (lane == bl) {
        #pragma unroll
        for (int s = 0; s < 31; ++s) ng[s] = ng[s + 1];
        ng[31] = -3.0e38f;
      }
    }
    __syncthreads();
    nc = 128;
  }

  // ---- positive fallback (pc > cap; never taken on this data)
  if (pc > 1024) {
    float pv[8];
    #pragma unroll
    for (int s = 0; s < 8; ++s) pv[s] = 3.0e38f;
    #pragma unroll 1
    for (int it = 0; it < 32; ++it) {
      int j0 = (it * 256 + tid) * 8;
      u16x8 pb = *(const u16x8*)(prow + j0);
      u16x8 mb = *(const u16x8*)(g_meta + j0);
      #pragma unroll
      for (int q = 0; q < 8; ++q) {
        if ((int)mb[q] != lab) continue;
        float v = bf2f(pb[q]);
        if (v < pv[7]) {
          #pragma unroll
          for (int s = 7; s >= 1; --s) pv[s] = (v < pv[s]) ? ((v < pv[s-1]) ? pv[s-1] : v) : pv[s];
          pv[0] = (v < pv[0]) ? v : pv[0];
        }
      }
    }
    __syncthreads();
    #pragma unroll 1
    for (int r = 0; r < 8; ++r) {
      float bv = pv[0]; int bl = lane;
      #pragma unroll
      for (int off = 32; off; off >>= 1) {
        float ov = __shfl_xor(bv, off); int ol = __shfl_xor(bl, off);
        bool t = ov < bv || (ov == bv && ol < bl);
        bv = t ? ov : bv; bl = t ? ol : bl;
      }
      if (lane == 0) s_pos[wid * 8 + r] = bv;
      if (lane == bl) {
        #pragma unroll
        for (int s = 0; s < 7; ++s) pv[s] = pv[s + 1];
        pv[7] = 3.0e38f;
      }
    }
    __syncthreads();
    pc = 32;
  }

  if (wid == 0) {                       // exact top-32 negatives from list
    float vals[8];
    #pragma unroll
    for (int q = 0; q < 8; ++q) { int ix = q * 64 + lane; vals[q] = ix < nc ? s_ncv[ix] : -3.0e38f; }
    float myv = -3.0e38f;
    #pragma unroll 1
    for (int r = 0; r < 32; ++r) {
      float bv = vals[0]; int bq = 0;
      #pragma unroll
      for (int q = 1; q < 8; ++q) { bool t = vals[q] > bv; bv = t ? vals[q] : bv; bq = t ? q : bq; }
      int bl = lane;
      #pragma unroll
      for (int off = 32; off; off >>= 1) {
        float ov = __shfl_xor(bv, off); int ol = __shfl_xor(bl, off);
        bool t = ov > bv || (ov == bv && ol < bl);
        bv = t ? ov : bv; bl = t ? ol : bl;
      }
      if (lane == bl) {
        #pragma unroll
        for (int q = 0; q < 8; ++q) vals[q] = (q == bq) ? -3.0e38f : vals[q];
      }
      if (lane == r) myv = bv;
    }
    if (lane < 32) g_neg[row * 32 + lane] = myv;
  } else if (wid == 2) {                // exact 8 smallest positives from list
    float vals[16];
    #pragma unroll
    for (int q = 0; q < 16; ++q) { int ix = q * 64 + lane; vals[q] = ix < pc ? s_pos[ix] : 3.0e38f; }
    float myv = 3.0e38f;
    #pragma unroll 1
    for (int r = 0; r < 8; ++r) {
      float bv = vals[0]; int bq = 0;
      #pragma unroll
      for (int q = 1; q < 16; ++q) { bool t = vals[q] < bv; bv = t ? vals[q] : bv; bq = t ? q : bq; }
      int bl = lane;
      #pragma unroll
      for (int off = 32; off; off >>= 1) {
        float ov = __shfl_xor(bv, off); int ol = __shfl_xor(bl, off);
        bool t = ov < bv || (ov == bv && ol < bl);
        bv = t ? ov : bv; bl = t ? ol : bl;
      }
      if (lane == bl) {
        #pragma unroll
        for (int q = 0; q < 16; ++q) vals[q] = (q == bq) ? 3.0e38f : vals[q];
      }
      if (lane == r) myv = bv;
    }
    if (lane < 8) g_pos[row * 8 + lane] = myv;
  }
}

// ---------------- per-row loss ----------------------------------------------
__global__ __launch_bounds__(256) void k_loss(const int* label) {
  int i = blockIdx.x * 256 + threadIdx.x;
  if (i >= NROW) return;
  float psum = g_clssum[label[i]];
  float nsum = g_clssum[155] - psum;
  int valid = (psum >= 8.0f) && (nsum >= 32.0f);
  float loss = 0.0f;
  if (valid) {
    const float invT = 1.25f;
    float nh[32], nr[32];
    float m1 = -3.0e38f, m2 = -3.0e38f;
    #pragma unroll
    for (int k = 0; k < 32; ++k) {
      nh[k] = g_neg[i * 32 + k] * invT; m1 = fmaxf(m1, nh[k]);
      int c = g_rndc[i * 32 + k]; c = ((unsigned)c < MEMN) ? c : 0;
      nr[k] = bf2f(g_pairsb[(size_t)i * MEMN + c]) * invT; m2 = fmaxf(m2, nr[k]);
    }
    float s1 = 0.0f, s2 = 0.0f;
    #pragma unroll
    for (int k = 0; k < 32; ++k) { s1 += expf(nh[k] - m1); s2 += expf(nr[k] - m2); }
    #pragma unroll
    for (int p = 0; p < 8; ++p) {
      float a = g_pos[i * 8 + p] * invT;
      { float m = fmaxf(a, m1); loss += m + logf(expf(a - m) + s1 * expf(m1 - m)) - a; }
      { float m = fmaxf(a, m2); loss += m + logf(expf(a - m) + s2 * expf(m2 - m)) - a; }
    }
  }
  g_rowloss[i] = loss;
  g_rowvalid[i] = valid;
}

__global__ __launch_bounds__(256) void k_final(float* out) {
  __shared__ float sl[256];
  __shared__ int sc[256];
  int t = threadIdx.x;
  float l = 0.0f; int c = 0;
  for (int i = t; i < NROW; i += 256) { l += g_rowloss[i]; c += g_rowvalid[i]; }
  sl[t] = l; sc[t] = c;
  __syncthreads();
  for (int s = 128; s > 0; s >>= 1) {
    if (t < s) { sl[t] += sl[t + s]; sc[t] += sc[t + s]; }
    __syncthreads();
  }
  if (t == 0) out[0] = (sc[0] > 0) ? sl[0] / ((float)sc[0] * 16.0f) : 0.0f;
}

// ---------------- launch ----------------------------------------------------
extern "C" void kernel_launch(void* const* d_in, const int* in_sizes, int n_in,
                              void* d_out, int out_size, void* d_ws, size_t ws_size,
                              hipStream_t stream) {
  const float* f          = (const float*)d_in[0];
  const float* W          = (const float*)d_in[1];
  const float* b          = (const float*)d_in[2];
  const float* Bank       = (const float*)d_in[3];
  const float* bank_flag  = (const float*)d_in[4];
  const int*   label      = (const int*)d_in[5];
  const long long* in_idx = (const long long*)d_in[6];
  const int*   label_all  = (const int*)d_in[7];
  float* out = (float*)d_out;

  hipLaunchKernelGGL(k_owner_init,    dim3(MEMN / 256), dim3(256), 0, stream);
  hipLaunchKernelGGL(k_owner_scatter, dim3(NROW / 256), dim3(256), 0, stream, in_idx);
  hipLaunchKernelGGL(k_meta,          dim3(MEMN / 256), dim3(256), 0, stream, bank_flag, label_all);
  hipLaunchKernelGGL(k_fn,            dim3(NROW),       dim3(256), 0, stream, f, W, b);
  hipLaunchKernelGGL(k_bank2,         dim3(MEMN / 4),   dim3(256), 0, stream, Bank);
  hipLaunchKernelGGL(k_rand,          dim3(NROW / 2),   dim3(512), 0, stream, label);
  hipLaunchKernelGGL(k_gemm,          dim3(4096),       dim3(256), 0, stream);
  hipLaunchKernelGGL(k_select,        dim3(NROW),       dim3(256), 0, stream, label);
  hipLaunchKernelGGL(k_loss,          dim3(NROW / 256), dim3(256), 0, stream, label);
  hipLaunchKernelGGL(k_final,         dim3(1),          dim3(256), 0, stream, out);
}